// Round 14
// baseline (2429.564 us; speedup 1.0000x reference)
//
#include <hip/hip_runtime.h>
#include <stdint.h>

// Problem constants
#define T_   512
#define B_   64
#define DIN  1024
#define HID  512
#define G3   1536     // 3*HID
#define NC   3072     // both dirs of gates
#define MROWS 32768   // T_*B_

typedef __bf16 bf16;
typedef __bf16 bf16x8 __attribute__((ext_vector_type(8)));
typedef float  f32x4  __attribute__((ext_vector_type(4)));

#define GLOBAL_AS __attribute__((address_space(1)))
#define LDS_AS    __attribute__((address_space(3)))

#define LDT(p) __hip_atomic_load((p), __ATOMIC_RELAXED, __HIP_MEMORY_SCOPE_AGENT)

__device__ __forceinline__ uint16_t f2bf_bits(float x){
  union{float f; uint32_t u;} v; v.f = x;
  uint32_t u = v.u;
  u += 0x7FFFu + ((u >> 16) & 1u);   // round-to-nearest-even
  return (uint16_t)(u >> 16);
}
__device__ __forceinline__ float bf2f_bits(uint16_t h){
  union{uint32_t u; float f;} v; v.u = ((uint32_t)h) << 16;
  return v.f;
}
__device__ __forceinline__ float sig_f(float x){
  return 1.f/(1.f + __expf(-x));
}
__device__ __forceinline__ float tanh_f(float x){
  return 1.f - 2.f/(1.f + __expf(2.f*x));
}
__device__ __forceinline__ bf16x8 as_bf16x8(uint4 u){
  union{uint4 a; bf16x8 b;} c; c.a = u; return c.b;
}

// ---------------------------------------------------------------- converts
__global__ void k_conv_emb(const float* __restrict__ src, uint16_t* __restrict__ dst, long n8){
  long i = (long)blockIdx.x*blockDim.x + threadIdx.x;
  if(i >= n8) return;
  const float4* s = (const float4*)src;
  float4 a = s[i*2], b = s[i*2+1];
  uint32_t p0 = (uint32_t)f2bf_bits(a.x) | ((uint32_t)f2bf_bits(a.y) << 16);
  uint32_t p1 = (uint32_t)f2bf_bits(a.z) | ((uint32_t)f2bf_bits(a.w) << 16);
  uint32_t p2 = (uint32_t)f2bf_bits(b.x) | ((uint32_t)f2bf_bits(b.y) << 16);
  uint32_t p3 = (uint32_t)f2bf_bits(b.z) | ((uint32_t)f2bf_bits(b.w) << 16);
  ((uint4*)dst)[i] = make_uint4(p0,p1,p2,p3);
}

__global__ void k_conv_wcat(const float* __restrict__ wf, const float* __restrict__ wb, uint16_t* __restrict__ dst, int n){
  int i = blockIdx.x*256 + threadIdx.x;
  if(i >= n) return;
  float v = (i < G3*DIN) ? wf[i] : wb[i - G3*DIN];
  dst[i] = f2bf_bits(v);
}

__global__ void k_conv_awt(const float* __restrict__ aw, uint16_t* __restrict__ dst, int n){
  int i = blockIdx.x*256 + threadIdx.x;
  if(i >= n) return;
  int e = i >> 10, d = i & 1023;
  dst[i] = f2bf_bits(aw[d*1024 + e]);   // transpose: awT[e][d]
}

// W_hh -> bf16, member-sliced, chunk-XOR-pre-swizzled (same layout as r6-r13).
__global__ void k_conv_whh(const float* __restrict__ wf, const float* __restrict__ wb, uint4* __restrict__ wmem){
  int idx = blockIdx.x*256 + threadIdx.x;   // 196608 total
  if(idx >= 2*16*96*64) return;
  int c  = idx & 63;
  int t2 = idx >> 6;
  int lc = t2 % 96;
  int t3 = t2 / 96;
  int member = t3 & 15, dir = t3 >> 4;
  int ct = lc >> 4, rr = lc & 15;
  int gcol = (ct >> 1)*512 + member*32 + (ct & 1)*16 + rr;
  int csrc = c ^ (lc & 7);
  const float* src = (dir ? wb : wf) + (size_t)gcol*512 + csrc*8;
  float4 f0 = *(const float4*)src;
  float4 f1 = *(const float4*)(src + 4);
  uint32_t p0 = (uint32_t)f2bf_bits(f0.x) | ((uint32_t)f2bf_bits(f0.y) << 16);
  uint32_t p1 = (uint32_t)f2bf_bits(f0.z) | ((uint32_t)f2bf_bits(f0.w) << 16);
  uint32_t p2 = (uint32_t)f2bf_bits(f1.x) | ((uint32_t)f2bf_bits(f1.y) << 16);
  uint32_t p3 = (uint32_t)f2bf_bits(f1.z) | ((uint32_t)f2bf_bits(f1.w) << 16);
  wmem[idx] = make_uint4(p0,p1,p2,p3);
}

// ---------------------------------------------------------------- GEMM: xp = emb @ Wcat^T + bias
// OUTPUT BLOCKED for k_recur: xp[dir][t][bg][member][g][16 rows][32 cols] bf16
__launch_bounds__(256)
__global__ void k_gemm_xp(const uint16_t* __restrict__ A, const uint16_t* __restrict__ Bw,
                          const float* __restrict__ bihf, const float* __restrict__ bihb,
                          uint16_t* __restrict__ C)
{
  __shared__ uint16_t lA[2][128*32];
  __shared__ uint16_t lB[2][128*32];
  const int K = 1024;
  int bn = blockIdx.x, bm = blockIdx.y;
  int tid = threadIdx.x;
  int lane = tid & 63, wid = tid >> 6;
  int wm = wid >> 1, wn = wid & 1;
  int rowBase = bm*128, colBase = bn*128;
  int rg = lane >> 4, rr = lane & 15;

  auto stage = [&](int buf, int kt){
    #pragma unroll
    for(int i=0;i<2;i++){
      int e = (i*256 + tid)*8;
      int r = e >> 5, c = e & 31;
      __builtin_amdgcn_global_load_lds((const GLOBAL_AS void*)(A + (size_t)(rowBase + r)*K + kt*32 + c),
                                       (LDS_AS void*)&lA[buf][e], 16, 0, 0);
    }
    #pragma unroll
    for(int i=0;i<2;i++){
      int e = (i*256 + tid)*8;
      int r = e >> 5, c = e & 31;
      __builtin_amdgcn_global_load_lds((const GLOBAL_AS void*)(Bw + (size_t)(colBase + r)*K + kt*32 + c),
                                       (LDS_AS void*)&lB[buf][e], 16, 0, 0);
    }
  };

  f32x4 acc[4][4];
  #pragma unroll
  for(int mi=0;mi<4;mi++)
    #pragma unroll
    for(int ni=0;ni<4;ni++) acc[mi][ni] = (f32x4){0.f,0.f,0.f,0.f};

  stage(0, 0);
  __syncthreads();
  for(int kt=0; kt<32; kt++){
    int buf = kt & 1;
    if(kt+1 < 32) stage(buf^1, kt+1);
    bf16x8 af[4], bfv[4];
    #pragma unroll
    for(int mi=0;mi<4;mi++)
      af[mi] = *(const bf16x8*)&lA[buf][(wm*64 + mi*16 + rr)*32 + rg*8];
    #pragma unroll
    for(int ni=0;ni<4;ni++)
      bfv[ni] = *(const bf16x8*)&lB[buf][(wn*64 + ni*16 + rr)*32 + rg*8];
    #pragma unroll
    for(int mi=0;mi<4;mi++)
      #pragma unroll
      for(int ni=0;ni<4;ni++)
        acc[mi][ni] = __builtin_amdgcn_mfma_f32_16x16x32_bf16(af[mi], bfv[ni], acc[mi][ni], 0,0,0);
    __syncthreads();
  }

  #pragma unroll
  for(int ni=0;ni<4;ni++){
    int col = colBase + wn*64 + ni*16 + rr;
    float bv = (col < G3) ? bihf[col] : bihb[col - G3];
    int dircol = (col >= G3) ? 1 : 0;
    int cm = col - dircol*G3;
    int g  = cm >> 9;
    int j  = cm & 511;
    int mem = j >> 5, cc = j & 31;
    #pragma unroll
    for(int mi=0;mi<4;mi++){
      int row0 = rowBase + wm*64 + mi*16 + rg*4;
      int tt = row0 >> 6;
      int b0 = row0 & 63;
      int bgx = b0 >> 4, rr0 = b0 & 15;
      size_t ob = (((((size_t)dircol*512 + tt)*4 + bgx)*16 + mem)*3 + g)*512 + rr0*32 + cc;
      C[ob]      = f2bf_bits(acc[mi][ni][0]+bv);
      C[ob+32]   = f2bf_bits(acc[mi][ni][1]+bv);
      C[ob+64]   = f2bf_bits(acc[mi][ni][2]+bv);
      C[ob+96]   = f2bf_bits(acc[mi][ni][3]+bv);
    }
  }
}

// ---------------------------------------------------------------- GEMM: attention, fused tanh + ctx_w dot
__launch_bounds__(256)
__global__ void k_gemm_att(const uint16_t* __restrict__ A, const uint16_t* __restrict__ Bw,
                           const float* __restrict__ attn_b, const float* __restrict__ ctx_w,
                           float* __restrict__ scores_raw)
{
  __shared__ uint16_t lA[2][128*32];
  __shared__ uint16_t lB[2][128*32];
  const int K = 1024;
  int bn = blockIdx.x, bm = blockIdx.y;
  int tid = threadIdx.x;
  int lane = tid & 63, wid = tid >> 6;
  int wm = wid >> 1, wn = wid & 1;
  int rowBase = bm*128, colBase = bn*128;
  int rg = lane >> 4, rr = lane & 15;

  auto stage = [&](int buf, int kt){
    #pragma unroll
    for(int i=0;i<2;i++){
      int e = (i*256 + tid)*8;
      int r = e >> 5, c = e & 31;
      __builtin_amdgcn_global_load_lds((const GLOBAL_AS void*)(A + (size_t)(rowBase + r)*K + kt*32 + c),
                                       (LDS_AS void*)&lA[buf][e], 16, 0, 0);
    }
    #pragma unroll
    for(int i=0;i<2;i++){
      int e = (i*256 + tid)*8;
      int r = e >> 5, c = e & 31;
      __builtin_amdgcn_global_load_lds((const GLOBAL_AS void*)(Bw + (size_t)(colBase + r)*K + kt*32 + c),
                                       (LDS_AS void*)&lB[buf][e], 16, 0, 0);
    }
  };

  f32x4 acc[4][4];
  #pragma unroll
  for(int mi=0;mi<4;mi++)
    #pragma unroll
    for(int ni=0;ni<4;ni++) acc[mi][ni] = (f32x4){0.f,0.f,0.f,0.f};

  stage(0, 0);
  __syncthreads();
  for(int kt=0; kt<32; kt++){
    int buf = kt & 1;
    if(kt+1 < 32) stage(buf^1, kt+1);
    bf16x8 af[4], bfv[4];
    #pragma unroll
    for(int mi=0;mi<4;mi++)
      af[mi] = *(const bf16x8*)&lA[buf][(wm*64 + mi*16 + rr)*32 + rg*8];
    #pragma unroll
    for(int ni=0;ni<4;ni++)
      bfv[ni] = *(const bf16x8*)&lB[buf][(wn*64 + ni*16 + rr)*32 + rg*8];
    #pragma unroll
    for(int mi=0;mi<4;mi++)
      #pragma unroll
      for(int ni=0;ni<4;ni++)
        acc[mi][ni] = __builtin_amdgcn_mfma_f32_16x16x32_bf16(af[mi], bfv[ni], acc[mi][ni], 0,0,0);
    __syncthreads();
  }

  float ab[4], cw[4];
  #pragma unroll
  for(int ni=0;ni<4;ni++){
    int col = colBase + wn*64 + ni*16 + rr;
    ab[ni] = attn_b[col];
    cw[ni] = ctx_w[col];
  }
  #pragma unroll
  for(int mi=0;mi<4;mi++){
    #pragma unroll
    for(int r=0;r<4;r++){
      float part = 0.f;
      #pragma unroll
      for(int ni=0;ni<4;ni++) part += tanhf(acc[mi][ni][r] + ab[ni]) * cw[ni];
      #pragma unroll
      for(int off=1; off<16; off<<=1) part += __shfl_xor(part, off);
      if(rr == 0){
        int row = rowBase + wm*64 + mi*16 + rg*4 + r;
        atomicAdd(&scores_raw[row], part);
      }
    }
  }
}

// ---------------------------------------------------------------- recurrence v12: dual-direction interleave + prefetch.
// WG = (bg, member), handles BOTH dirs alternately (64 WGs). Each phase prefetches the
// other phase's tagged h loads + xp, hiding the LLC detect RT under compute.
// W for both dirs in registers (64 VGPR/lane). Retry fallback = r13-proven loop.
__launch_bounds__(768, 3)
__global__ void k_recur(const uint16_t* __restrict__ xp,     // blocked [dir][T][bg][member][3][16][32]
                        const uint4* __restrict__ wmem,      // pre-swizzled W slices
                        const float* __restrict__ bhhf, const float* __restrict__ bhhb,
                        unsigned long long* __restrict__ tagbuf,
                        uint16_t* __restrict__ f_out)
{
  __shared__ uint16_t hl[16*512];        // 16 KB, chunk-XOR swizzled (reused per phase)
  __shared__ float    ghl[2*6*16*17];    // 12.75 KB (reused per phase)

  int bid = blockIdx.x;
  int bg = bid & 3, member = bid >> 2;   // 64 WGs
  int jb = member*32;
  int tid = threadIdx.x;
  int lane = tid & 63, w = tid >> 6;
  int rr = lane & 15, rg = lane >> 4;
  int ct = w >> 1, kh = w & 1;
  int xm = rr & 7;

  // ---- W fragments for BOTH dirs -> registers (16 x 16B per lane) ----
  const uint4* wsl0 = wmem + (size_t)member*6144 + (ct*16 + rr)*64;
  const uint4* wsl1 = wmem + (size_t)(16 + member)*6144 + (ct*16 + rr)*64;
  uint4 wa0 = wsl0[(kh*32 +  0 + rg) ^ xm];
  uint4 wa1 = wsl0[(kh*32 +  4 + rg) ^ xm];
  uint4 wa2 = wsl0[(kh*32 +  8 + rg) ^ xm];
  uint4 wa3 = wsl0[(kh*32 + 12 + rg) ^ xm];
  uint4 wa4 = wsl0[(kh*32 + 16 + rg) ^ xm];
  uint4 wa5 = wsl0[(kh*32 + 20 + rg) ^ xm];
  uint4 wa6 = wsl0[(kh*32 + 24 + rg) ^ xm];
  uint4 wa7 = wsl0[(kh*32 + 28 + rg) ^ xm];
  uint4 wb0 = wsl1[(kh*32 +  0 + rg) ^ xm];
  uint4 wb1 = wsl1[(kh*32 +  4 + rg) ^ xm];
  uint4 wb2 = wsl1[(kh*32 +  8 + rg) ^ xm];
  uint4 wb3 = wsl1[(kh*32 + 12 + rg) ^ xm];
  uint4 wb4 = wsl1[(kh*32 + 16 + rg) ^ xm];
  uint4 wb5 = wsl1[(kh*32 + 20 + rg) ^ xm];
  uint4 wb6 = wsl1[(kh*32 + 24 + rg) ^ xm];
  uint4 wb7 = wsl1[(kh*32 + 28 + rg) ^ xm];
  asm volatile("" :: "v"(wa0.x), "v"(wa0.y), "v"(wa0.z), "v"(wa0.w),
                     "v"(wa1.x), "v"(wa1.y), "v"(wa1.z), "v"(wa1.w));
  asm volatile("" :: "v"(wa2.x), "v"(wa2.y), "v"(wa2.z), "v"(wa2.w),
                     "v"(wa3.x), "v"(wa3.y), "v"(wa3.z), "v"(wa3.w));
  asm volatile("" :: "v"(wa4.x), "v"(wa4.y), "v"(wa4.z), "v"(wa4.w),
                     "v"(wa5.x), "v"(wa5.y), "v"(wa5.z), "v"(wa5.w));
  asm volatile("" :: "v"(wa6.x), "v"(wa6.y), "v"(wa6.z), "v"(wa6.w),
                     "v"(wa7.x), "v"(wa7.y), "v"(wa7.z), "v"(wa7.w));
  asm volatile("" :: "v"(wb0.x), "v"(wb0.y), "v"(wb0.z), "v"(wb0.w),
                     "v"(wb1.x), "v"(wb1.y), "v"(wb1.z), "v"(wb1.w));
  asm volatile("" :: "v"(wb2.x), "v"(wb2.y), "v"(wb2.z), "v"(wb2.w),
                     "v"(wb3.x), "v"(wb3.y), "v"(wb3.z), "v"(wb3.w));
  asm volatile("" :: "v"(wb4.x), "v"(wb4.y), "v"(wb4.z), "v"(wb4.w),
                     "v"(wb5.x), "v"(wb5.y), "v"(wb5.z), "v"(wb5.w));
  asm volatile("" :: "v"(wb6.x), "v"(wb6.y), "v"(wb6.z), "v"(wb6.w),
                     "v"(wb7.x), "v"(wb7.y), "v"(wb7.z), "v"(wb7.w));

  for(int i = tid; i < 2*6*16*17; i += 768) ghl[i] = 0.f;

  int gcol = tid & 31;
  float bR0=0,bZ0=0,bN0=0,bR1=0,bZ1=0,bN1=0, hA=0.f, hB=0.f;
  if(tid < 512){
    bR0 = bhhf[jb + gcol]; bZ0 = bhhf[512 + jb + gcol]; bN0 = bhhf[1024 + jb + gcol];
    bR1 = bhhb[jb + gcol]; bZ1 = bhhb[512 + jb + gcol]; bN1 = bhhb[1024 + jb + gcol];
  }

  int srow = tid >> 5, sbase = tid & 31;
  int cswz = (sbase >> 2) ^ (srow & 7);
  int lpos0 = srow*512 + cswz*8 + (sbase & 3)*2;

  unsigned long long pA0=0,pA1=0,pA2=0,pA3=0,pA4=0,pA5=0,pA6=0,pA7=0;
  unsigned long long pB0=0,pB1=0,pB2=0,pB3=0,pB4=0,pB5=0,pB6=0,pB7=0;
  uint16_t xAr=0,xAz=0,xAn=0, xBr=0,xBz=0,xBn=0;

  // synchronous xpA for t=0 (dir0, trow 0)
  if(tid < 512){
    const uint16_t* xb = xp + (((size_t)bg*16 + member)*3)*512;
    xAr = xb[tid]; xAz = xb[512 + tid]; xAn = xb[1024 + tid];
  }
  __syncthreads();   // ghl zeroed

  #pragma unroll 1
  for(int t = 0; t < 512; t++){
    // =================== PHASE A : dir 0, row t ===================
    if(t > 0 && tid < 512){
      const unsigned long long* tb =
        tagbuf + ((size_t)(((t-1)&1)*4 + bg)*16 + srow)*256 + sbase;
      unsigned want = (unsigned)t;
      bool ok = ((unsigned)pA0==want)&((unsigned)pA1==want)&((unsigned)pA2==want)&((unsigned)pA3==want)
              & ((unsigned)pA4==want)&((unsigned)pA5==want)&((unsigned)pA6==want)&((unsigned)pA7==want);
      while(!ok){
        pA0 = LDT(tb+0);   pA1 = LDT(tb+32);  pA2 = LDT(tb+64);  pA3 = LDT(tb+96);
        pA4 = LDT(tb+128); pA5 = LDT(tb+160); pA6 = LDT(tb+192); pA7 = LDT(tb+224);
        ok = ((unsigned)pA0==want)&((unsigned)pA1==want)&((unsigned)pA2==want)&((unsigned)pA3==want)
           & ((unsigned)pA4==want)&((unsigned)pA5==want)&((unsigned)pA6==want)&((unsigned)pA7==want);
      }
      *(uint32_t*)&hl[lpos0 +   0] = (uint32_t)(pA0 >> 32);
      *(uint32_t*)&hl[lpos0 +  64] = (uint32_t)(pA1 >> 32);
      *(uint32_t*)&hl[lpos0 + 128] = (uint32_t)(pA2 >> 32);
      *(uint32_t*)&hl[lpos0 + 192] = (uint32_t)(pA3 >> 32);
      *(uint32_t*)&hl[lpos0 + 256] = (uint32_t)(pA4 >> 32);
      *(uint32_t*)&hl[lpos0 + 320] = (uint32_t)(pA5 >> 32);
      *(uint32_t*)&hl[lpos0 + 384] = (uint32_t)(pA6 >> 32);
      *(uint32_t*)&hl[lpos0 + 448] = (uint32_t)(pA7 >> 32);
    }
    // prefetch phase-B tags (this t) + xpB (dir1, row 511-t)
    if(tid < 512){
      if(t > 0){
        const unsigned long long* tb =
          tagbuf + ((size_t)((2 + ((t-1)&1))*4 + bg)*16 + srow)*256 + sbase;
        pB0 = LDT(tb+0);   pB1 = LDT(tb+32);  pB2 = LDT(tb+64);  pB3 = LDT(tb+96);
        pB4 = LDT(tb+128); pB5 = LDT(tb+160); pB6 = LDT(tb+192); pB7 = LDT(tb+224);
      }
      const uint16_t* xb = xp + (((((size_t)512 + (511 - t))*4 + bg)*16 + member)*3)*512;
      xBr = xb[tid]; xBz = xb[512 + tid]; xBn = xb[1024 + tid];
    }
    __syncthreads();   // A1: hl ready
    if(t > 0){
      f32x4 acc = (f32x4){0.f,0.f,0.f,0.f};
      bf16x8 a0 = *(const bf16x8*)&hl[rr*512 + ((kh*32 +  0 + rg) ^ xm)*8];
      acc = __builtin_amdgcn_mfma_f32_16x16x32_bf16(a0, as_bf16x8(wa0), acc, 0,0,0);
      bf16x8 a1 = *(const bf16x8*)&hl[rr*512 + ((kh*32 +  4 + rg) ^ xm)*8];
      acc = __builtin_amdgcn_mfma_f32_16x16x32_bf16(a1, as_bf16x8(wa1), acc, 0,0,0);
      bf16x8 a2 = *(const bf16x8*)&hl[rr*512 + ((kh*32 +  8 + rg) ^ xm)*8];
      acc = __builtin_amdgcn_mfma_f32_16x16x32_bf16(a2, as_bf16x8(wa2), acc, 0,0,0);
      bf16x8 a3 = *(const bf16x8*)&hl[rr*512 + ((kh*32 + 12 + rg) ^ xm)*8];
      acc = __builtin_amdgcn_mfma_f32_16x16x32_bf16(a3, as_bf16x8(wa3), acc, 0,0,0);
      bf16x8 a4 = *(const bf16x8*)&hl[rr*512 + ((kh*32 + 16 + rg) ^ xm)*8];
      acc = __builtin_amdgcn_mfma_f32_16x16x32_bf16(a4, as_bf16x8(wa4), acc, 0,0,0);
      bf16x8 a5 = *(const bf16x8*)&hl[rr*512 + ((kh*32 + 20 + rg) ^ xm)*8];
      acc = __builtin_amdgcn_mfma_f32_16x16x32_bf16(a5, as_bf16x8(wa5), acc, 0,0,0);
      bf16x8 a6 = *(const bf16x8*)&hl[rr*512 + ((kh*32 + 24 + rg) ^ xm)*8];
      acc = __builtin_amdgcn_mfma_f32_16x16x32_bf16(a6, as_bf16x8(wa6), acc, 0,0,0);
      bf16x8 a7 = *(const bf16x8*)&hl[rr*512 + ((kh*32 + 28 + rg) ^ xm)*8];
      acc = __builtin_amdgcn_mfma_f32_16x16x32_bf16(a7, as_bf16x8(wa7), acc, 0,0,0);
      #pragma unroll
      for(int j = 0; j < 4; j++)
        ghl[((kh*6 + ct)*16 + rg*4 + j)*17 + rr] = acc[j];
    }
    __syncthreads();   // A2: ghl ready
    if(tid < 512){
      int grow = tid >> 5;
      int c16 = gcol >> 4, cc = gcol & 15;
      float gR = ghl[((0 + c16)*16 + grow)*17 + cc] + ghl[((6  + c16)*16 + grow)*17 + cc] + bR0;
      float gZ = ghl[((2 + c16)*16 + grow)*17 + cc] + ghl[((8  + c16)*16 + grow)*17 + cc] + bZ0;
      float gN = ghl[((4 + c16)*16 + grow)*17 + cc] + ghl[((10 + c16)*16 + grow)*17 + cc] + bN0;
      float rv = sig_f(bf2f_bits(xAr) + gR);
      float zv = sig_f(bf2f_bits(xAz) + gZ);
      float nv = tanh_f(bf2f_bits(xAn) + rv*gN);
      float hnew = (1.f - zv)*nv + zv*hA;
      hA = hnew;
      unsigned hb = (unsigned)f2bf_bits(hnew);
      unsigned nb = (unsigned)__shfl_down((int)hb, 1);
      if((tid & 1) == 0){
        unsigned pk = hb | (nb << 16);
        int slot = member*16 + (gcol >> 1);
        unsigned long long pv = ((unsigned long long)pk << 32) | (unsigned)(t + 1);
        __hip_atomic_store(
          tagbuf + ((size_t)((t&1)*4 + bg)*16 + grow)*256 + slot,
          pv, __ATOMIC_RELAXED, __HIP_MEMORY_SCOPE_AGENT);
        *(unsigned*)&f_out[((size_t)t*64 + bg*16 + grow)*1024 + jb + gcol] = pk;
      }
    }

    // =================== PHASE B : dir 1, row 511-t ===================
    if(t > 0 && tid < 512){
      const unsigned long long* tb =
        tagbuf + ((size_t)((2 + ((t-1)&1))*4 + bg)*16 + srow)*256 + sbase;
      unsigned want = (unsigned)t;
      bool ok = ((unsigned)pB0==want)&((unsigned)pB1==want)&((unsigned)pB2==want)&((unsigned)pB3==want)
              & ((unsigned)pB4==want)&((unsigned)pB5==want)&((unsigned)pB6==want)&((unsigned)pB7==want);
      while(!ok){
        pB0 = LDT(tb+0);   pB1 = LDT(tb+32);  pB2 = LDT(tb+64);  pB3 = LDT(tb+96);
        pB4 = LDT(tb+128); pB5 = LDT(tb+160); pB6 = LDT(tb+192); pB7 = LDT(tb+224);
        ok = ((unsigned)pB0==want)&((unsigned)pB1==want)&((unsigned)pB2==want)&((unsigned)pB3==want)
           & ((unsigned)pB4==want)&((unsigned)pB5==want)&((unsigned)pB6==want)&((unsigned)pB7==want);
      }
      *(uint32_t*)&hl[lpos0 +   0] = (uint32_t)(pB0 >> 32);
      *(uint32_t*)&hl[lpos0 +  64] = (uint32_t)(pB1 >> 32);
      *(uint32_t*)&hl[lpos0 + 128] = (uint32_t)(pB2 >> 32);
      *(uint32_t*)&hl[lpos0 + 192] = (uint32_t)(pB3 >> 32);
      *(uint32_t*)&hl[lpos0 + 256] = (uint32_t)(pB4 >> 32);
      *(uint32_t*)&hl[lpos0 + 320] = (uint32_t)(pB5 >> 32);
      *(uint32_t*)&hl[lpos0 + 384] = (uint32_t)(pB6 >> 32);
      *(uint32_t*)&hl[lpos0 + 448] = (uint32_t)(pB7 >> 32);
    }
    // prefetch phase-A tags for t+1 + xpA (dir0, row t+1)
    if(tid < 512){
      const unsigned long long* tb =
        tagbuf + ((size_t)((t&1)*4 + bg)*16 + srow)*256 + sbase;
      pA0 = LDT(tb+0);   pA1 = LDT(tb+32);  pA2 = LDT(tb+64);  pA3 = LDT(tb+96);
      pA4 = LDT(tb+128); pA5 = LDT(tb+160); pA6 = LDT(tb+192); pA7 = LDT(tb+224);
      const uint16_t* xb = xp + (((((size_t)(t + 1))*4 + bg)*16 + member)*3)*512;
      xAr = xb[tid]; xAz = xb[512 + tid]; xAn = xb[1024 + tid];
    }
    __syncthreads();   // B1: hl ready
    if(t > 0){
      f32x4 acc = (f32x4){0.f,0.f,0.f,0.f};
      bf16x8 a0 = *(const bf16x8*)&hl[rr*512 + ((kh*32 +  0 + rg) ^ xm)*8];
      acc = __builtin_amdgcn_mfma_f32_16x16x32_bf16(a0, as_bf16x8(wb0), acc, 0,0,0);
      bf16x8 a1 = *(const bf16x8*)&hl[rr*512 + ((kh*32 +  4 + rg) ^ xm)*8];
      acc = __builtin_amdgcn_mfma_f32_16x16x32_bf16(a1, as_bf16x8(wb1), acc, 0,0,0);
      bf16x8 a2 = *(const bf16x8*)&hl[rr*512 + ((kh*32 +  8 + rg) ^ xm)*8];
      acc = __builtin_amdgcn_mfma_f32_16x16x32_bf16(a2, as_bf16x8(wb2), acc, 0,0,0);
      bf16x8 a3 = *(const bf16x8*)&hl[rr*512 + ((kh*32 + 12 + rg) ^ xm)*8];
      acc = __builtin_amdgcn_mfma_f32_16x16x32_bf16(a3, as_bf16x8(wb3), acc, 0,0,0);
      bf16x8 a4 = *(const bf16x8*)&hl[rr*512 + ((kh*32 + 16 + rg) ^ xm)*8];
      acc = __builtin_amdgcn_mfma_f32_16x16x32_bf16(a4, as_bf16x8(wb4), acc, 0,0,0);
      bf16x8 a5 = *(const bf16x8*)&hl[rr*512 + ((kh*32 + 20 + rg) ^ xm)*8];
      acc = __builtin_amdgcn_mfma_f32_16x16x32_bf16(a5, as_bf16x8(wb5), acc, 0,0,0);
      bf16x8 a6 = *(const bf16x8*)&hl[rr*512 + ((kh*32 + 24 + rg) ^ xm)*8];
      acc = __builtin_amdgcn_mfma_f32_16x16x32_bf16(a6, as_bf16x8(wb6), acc, 0,0,0);
      bf16x8 a7 = *(const bf16x8*)&hl[rr*512 + ((kh*32 + 28 + rg) ^ xm)*8];
      acc = __builtin_amdgcn_mfma_f32_16x16x32_bf16(a7, as_bf16x8(wb7), acc, 0,0,0);
      #pragma unroll
      for(int j = 0; j < 4; j++)
        ghl[((kh*6 + ct)*16 + rg*4 + j)*17 + rr] = acc[j];
    }
    __syncthreads();   // B2: ghl ready
    if(tid < 512){
      int grow = tid >> 5;
      int c16 = gcol >> 4, cc = gcol & 15;
      float gR = ghl[((0 + c16)*16 + grow)*17 + cc] + ghl[((6  + c16)*16 + grow)*17 + cc] + bR1;
      float gZ = ghl[((2 + c16)*16 + grow)*17 + cc] + ghl[((8  + c16)*16 + grow)*17 + cc] + bZ1;
      float gN = ghl[((4 + c16)*16 + grow)*17 + cc] + ghl[((10 + c16)*16 + grow)*17 + cc] + bN1;
      float rv = sig_f(bf2f_bits(xBr) + gR);
      float zv = sig_f(bf2f_bits(xBz) + gZ);
      float nv = tanh_f(bf2f_bits(xBn) + rv*gN);
      float hnew = (1.f - zv)*nv + zv*hB;
      hB = hnew;
      unsigned hb = (unsigned)f2bf_bits(hnew);
      unsigned nb = (unsigned)__shfl_down((int)hb, 1);
      if((tid & 1) == 0){
        unsigned pk = hb | (nb << 16);
        int slot = member*16 + (gcol >> 1);
        unsigned long long pv = ((unsigned long long)pk << 32) | (unsigned)(t + 1);
        __hip_atomic_store(
          tagbuf + ((size_t)((2 + (t&1))*4 + bg)*16 + grow)*256 + slot,
          pv, __ATOMIC_RELAXED, __HIP_MEMORY_SCOPE_AGENT);
        *(unsigned*)&f_out[((size_t)(511 - t)*64 + bg*16 + grow)*1024 + 512 + jb + gcol] = pk;
      }
    }
  }
}

// ---------------------------------------------------------------- softmax over T per batch
__global__ void k_softmax(const float* __restrict__ scores_raw, float* __restrict__ wsm){
  __shared__ float sv[512];
  __shared__ float red[8];
  int b = blockIdx.x;
  int tid = threadIdx.x;
  float mymax = -1e30f;
  for(int t = tid; t < 512; t += 256){
    float s = tanhf(scores_raw[t*64 + b]);
    sv[t] = s;
    mymax = fmaxf(mymax, s);
  }
  #pragma unroll
  for(int off=1; off<64; off<<=1) mymax = fmaxf(mymax, __shfl_xor(mymax, off));
  if((tid&63)==0) red[tid>>6] = mymax;
  __syncthreads();
  float bmax = fmaxf(fmaxf(red[0],red[1]), fmaxf(red[2],red[3]));
  __syncthreads();
  float mysum = 0.f;
  for(int t = tid; t < 512; t += 256){
    float e = __expf(sv[t] - bmax);
    sv[t] = e;
    mysum += e;
  }
  #pragma unroll
  for(int off=1; off<64; off<<=1) mysum += __shfl_xor(mysum, off);
  if((tid&63)==0) red[tid>>6] = mysum;
  __syncthreads();
  float inv = 1.f/(red[0]+red[1]+red[2]+red[3]);
  for(int t = tid; t < 512; t += 256) wsm[b*512 + t] = sv[t]*inv;
}

// ---------------------------------------------------------------- ctx[b,d] = sum_t w[b,t] f[t,b,d]
__global__ void k_ctx(const uint16_t* __restrict__ f_out, const float* __restrict__ wsm, float* __restrict__ ctx){
  __shared__ float wloc[512];
  int b = blockIdx.x >> 2, chunk = blockIdx.x & 3;
  int tid = threadIdx.x;
  for(int t = tid; t < 512; t += 256) wloc[t] = wsm[b*512 + t];
  __syncthreads();
  int d = chunk*256 + tid;
  float acc = 0.f;
  #pragma unroll 8
  for(int t = 0; t < 512; t++)
    acc += wloc[t] * bf2f_bits(f_out[(size_t)(t*64 + b)*1024 + d]);
  ctx[b*1024 + d] = acc;
}

// ---------------------------------------------------------------- classifier
__global__ void k_cls1(const float* __restrict__ ctx, const float* __restrict__ w1,
                       const float* __restrict__ b1, float* __restrict__ hid){
  int idx = blockIdx.x*256 + threadIdx.x;   // 32768
  int b = idx >> 9, h = idx & 511;
  float acc = b1[h];
  for(int d = 0; d < 1024; d++) acc += ctx[b*1024 + d] * w1[d*512 + h];
  hid[idx] = fmaxf(acc, 0.f);
}

__global__ void k_cls2(const float* __restrict__ hid, const float* __restrict__ w2,
                       const float* __restrict__ b2, float* __restrict__ out){
  int idx = threadIdx.x;   // 640
  if(idx >= 640) return;
  int b = idx / 10, o = idx % 10;
  float acc = b2[o];
  for(int h = 0; h < 512; h++) acc += hid[b*512 + h] * w2[h*10 + o];
  out[idx] = acc;
}

// ---------------------------------------------------------------- launch
extern "C" void kernel_launch(void* const* d_in, const int* in_sizes, int n_in,
                              void* d_out, int out_size, void* d_ws, size_t ws_size,
                              hipStream_t stream)
{
  const float* emb    = (const float*)d_in[1];
  const float* w_ih_f = (const float*)d_in[2];
  const float* w_hh_f = (const float*)d_in[3];
  const float* b_ih_f = (const float*)d_in[4];
  const float* b_hh_f = (const float*)d_in[5];
  const float* w_ih_b = (const float*)d_in[6];
  const float* w_hh_b = (const float*)d_in[7];
  const float* b_ih_b = (const float*)d_in[8];
  const float* b_hh_b = (const float*)d_in[9];
  const float* attn_w = (const float*)d_in[10];
  const float* attn_b = (const float*)d_in[11];
  const float* ctx_w  = (const float*)d_in[12];
  const float* cls_w1 = (const float*)d_in[13];
  const float* cls_b1 = (const float*)d_in[14];
  const float* cls_w2 = (const float*)d_in[15];
  const float* cls_b2 = (const float*)d_in[16];
  float* out = (float*)d_out;

  char* ws = (char*)d_ws;
  size_t off = 0;
  auto alloc = [&](size_t bytes){ void* p = ws + off; off += (bytes + 255) & ~(size_t)255; return p; };
  uint16_t* femb = (uint16_t*)alloc((size_t)MROWS*DIN*2);      // emb bf16, later overlaid by f_out
  uint16_t* wcat = (uint16_t*)alloc((size_t)NC*DIN*2);
  uint16_t* xp   = (uint16_t*)alloc((size_t)MROWS*NC*2);       // blocked layout
  uint16_t* awT  = (uint16_t*)alloc((size_t)1024*1024*2);
  uint4*    wmem = (uint4*)alloc((size_t)2*16*96*64*16);       // 3 MB pre-swizzled W
  unsigned long long* tagbuf = (unsigned long long*)alloc((size_t)2*2*4*16*256*8);  // 1 MB
  float* scraw   = (float*)alloc((size_t)MROWS*4);
  float* wsm     = (float*)alloc((size_t)B_*T_*4);
  float* ctx     = (float*)alloc((size_t)B_*1024*4);
  float* hid     = (float*)alloc((size_t)B_*512*4);

  (void)hipMemsetAsync(tagbuf, 0, (size_t)2*2*4*16*256*8, stream);
  (void)hipMemsetAsync(scraw, 0, (size_t)MROWS*4, stream);

  k_conv_emb<<<16384, 256, 0, stream>>>(emb, femb, (long)MROWS*DIN/8);
  k_conv_wcat<<<12288, 256, 0, stream>>>(w_ih_f, w_ih_b, wcat, NC*DIN);
  k_conv_awt<<<4096, 256, 0, stream>>>(attn_w, awT, 1024*1024);
  k_conv_whh<<<768, 256, 0, stream>>>(w_hh_f, w_hh_b, wmem);

  k_gemm_xp<<<dim3(24,256), 256, 0, stream>>>(femb, wcat, b_ih_f, b_ih_b, xp);

  k_recur<<<64, 768, 0, stream>>>(xp, wmem, b_hh_f, b_hh_b, tagbuf, femb /* = f_out */);

  k_gemm_att<<<dim3(8,256), 256, 0, stream>>>(femb, awT, attn_b, ctx_w, scraw);
  k_softmax<<<64, 256, 0, stream>>>(scraw, wsm);
  k_ctx<<<256, 256, 0, stream>>>(femb, wsm, ctx);
  k_cls1<<<128, 256, 0, stream>>>(ctx, cls_w1, cls_b1, hid);
  k_cls2<<<1, 640, 0, stream>>>(hid, cls_w2, cls_b2, out);
}

// Round 15
// 1696.861 us; speedup vs baseline: 1.4318x; 1.4318x over previous
//
#include <hip/hip_runtime.h>
#include <stdint.h>

// Problem constants
#define T_   512
#define B_   64
#define DIN  1024
#define HID  512
#define G3   1536     // 3*HID
#define NC   3072     // both dirs of gates
#define MROWS 32768   // T_*B_

typedef __bf16 bf16;
typedef __bf16 bf16x8 __attribute__((ext_vector_type(8)));
typedef float  f32x4  __attribute__((ext_vector_type(4)));

#define GLOBAL_AS __attribute__((address_space(1)))
#define LDS_AS    __attribute__((address_space(3)))

#define LDT(p) __hip_atomic_load((p), __ATOMIC_RELAXED, __HIP_MEMORY_SCOPE_AGENT)

__device__ __forceinline__ uint16_t f2bf_bits(float x){
  union{float f; uint32_t u;} v; v.f = x;
  uint32_t u = v.u;
  u += 0x7FFFu + ((u >> 16) & 1u);   // round-to-nearest-even
  return (uint16_t)(u >> 16);
}
__device__ __forceinline__ float bf2f_bits(uint16_t h){
  union{uint32_t u; float f;} v; v.u = ((uint32_t)h) << 16;
  return v.f;
}
__device__ __forceinline__ float sig_f(float x){
  return 1.f/(1.f + __expf(-x));
}
__device__ __forceinline__ float tanh_f(float x){
  return 1.f - 2.f/(1.f + __expf(2.f*x));
}
__device__ __forceinline__ bf16x8 as_bf16x8(uint4 u){
  union{uint4 a; bf16x8 b;} c; c.a = u; return c.b;
}

// ---------------------------------------------------------------- converts
__global__ void k_conv_emb(const float* __restrict__ src, uint16_t* __restrict__ dst, long n8){
  long i = (long)blockIdx.x*blockDim.x + threadIdx.x;
  if(i >= n8) return;
  const float4* s = (const float4*)src;
  float4 a = s[i*2], b = s[i*2+1];
  uint32_t p0 = (uint32_t)f2bf_bits(a.x) | ((uint32_t)f2bf_bits(a.y) << 16);
  uint32_t p1 = (uint32_t)f2bf_bits(a.z) | ((uint32_t)f2bf_bits(a.w) << 16);
  uint32_t p2 = (uint32_t)f2bf_bits(b.x) | ((uint32_t)f2bf_bits(b.y) << 16);
  uint32_t p3 = (uint32_t)f2bf_bits(b.z) | ((uint32_t)f2bf_bits(b.w) << 16);
  ((uint4*)dst)[i] = make_uint4(p0,p1,p2,p3);
}

__global__ void k_conv_wcat(const float* __restrict__ wf, const float* __restrict__ wb, uint16_t* __restrict__ dst, int n){
  int i = blockIdx.x*256 + threadIdx.x;
  if(i >= n) return;
  float v = (i < G3*DIN) ? wf[i] : wb[i - G3*DIN];
  dst[i] = f2bf_bits(v);
}

__global__ void k_conv_awt(const float* __restrict__ aw, uint16_t* __restrict__ dst, int n){
  int i = blockIdx.x*256 + threadIdx.x;
  if(i >= n) return;
  int e = i >> 10, d = i & 1023;
  dst[i] = f2bf_bits(aw[d*1024 + e]);   // transpose: awT[e][d]
}

// W_hh -> bf16, member-sliced, chunk-XOR-pre-swizzled (same layout as r6-r13).
__global__ void k_conv_whh(const float* __restrict__ wf, const float* __restrict__ wb, uint4* __restrict__ wmem){
  int idx = blockIdx.x*256 + threadIdx.x;   // 196608 total
  if(idx >= 2*16*96*64) return;
  int c  = idx & 63;
  int t2 = idx >> 6;
  int lc = t2 % 96;
  int t3 = t2 / 96;
  int member = t3 & 15, dir = t3 >> 4;
  int ct = lc >> 4, rr = lc & 15;
  int gcol = (ct >> 1)*512 + member*32 + (ct & 1)*16 + rr;
  int csrc = c ^ (lc & 7);
  const float* src = (dir ? wb : wf) + (size_t)gcol*512 + csrc*8;
  float4 f0 = *(const float4*)src;
  float4 f1 = *(const float4*)(src + 4);
  uint32_t p0 = (uint32_t)f2bf_bits(f0.x) | ((uint32_t)f2bf_bits(f0.y) << 16);
  uint32_t p1 = (uint32_t)f2bf_bits(f0.z) | ((uint32_t)f2bf_bits(f0.w) << 16);
  uint32_t p2 = (uint32_t)f2bf_bits(f1.x) | ((uint32_t)f2bf_bits(f1.y) << 16);
  uint32_t p3 = (uint32_t)f2bf_bits(f1.z) | ((uint32_t)f2bf_bits(f1.w) << 16);
  wmem[idx] = make_uint4(p0,p1,p2,p3);
}

// ---------------------------------------------------------------- GEMM: xp = emb @ Wcat^T + bias
// OUTPUT BLOCKED for k_recur: xp[dir][t][bg][member][g][16 rows][32 cols] bf16
__launch_bounds__(256)
__global__ void k_gemm_xp(const uint16_t* __restrict__ A, const uint16_t* __restrict__ Bw,
                          const float* __restrict__ bihf, const float* __restrict__ bihb,
                          uint16_t* __restrict__ C)
{
  __shared__ uint16_t lA[2][128*32];
  __shared__ uint16_t lB[2][128*32];
  const int K = 1024;
  int bn = blockIdx.x, bm = blockIdx.y;
  int tid = threadIdx.x;
  int lane = tid & 63, wid = tid >> 6;
  int wm = wid >> 1, wn = wid & 1;
  int rowBase = bm*128, colBase = bn*128;
  int rg = lane >> 4, rr = lane & 15;

  auto stage = [&](int buf, int kt){
    #pragma unroll
    for(int i=0;i<2;i++){
      int e = (i*256 + tid)*8;
      int r = e >> 5, c = e & 31;
      __builtin_amdgcn_global_load_lds((const GLOBAL_AS void*)(A + (size_t)(rowBase + r)*K + kt*32 + c),
                                       (LDS_AS void*)&lA[buf][e], 16, 0, 0);
    }
    #pragma unroll
    for(int i=0;i<2;i++){
      int e = (i*256 + tid)*8;
      int r = e >> 5, c = e & 31;
      __builtin_amdgcn_global_load_lds((const GLOBAL_AS void*)(Bw + (size_t)(colBase + r)*K + kt*32 + c),
                                       (LDS_AS void*)&lB[buf][e], 16, 0, 0);
    }
  };

  f32x4 acc[4][4];
  #pragma unroll
  for(int mi=0;mi<4;mi++)
    #pragma unroll
    for(int ni=0;ni<4;ni++) acc[mi][ni] = (f32x4){0.f,0.f,0.f,0.f};

  stage(0, 0);
  __syncthreads();
  for(int kt=0; kt<32; kt++){
    int buf = kt & 1;
    if(kt+1 < 32) stage(buf^1, kt+1);
    bf16x8 af[4], bfv[4];
    #pragma unroll
    for(int mi=0;mi<4;mi++)
      af[mi] = *(const bf16x8*)&lA[buf][(wm*64 + mi*16 + rr)*32 + rg*8];
    #pragma unroll
    for(int ni=0;ni<4;ni++)
      bfv[ni] = *(const bf16x8*)&lB[buf][(wn*64 + ni*16 + rr)*32 + rg*8];
    #pragma unroll
    for(int mi=0;mi<4;mi++)
      #pragma unroll
      for(int ni=0;ni<4;ni++)
        acc[mi][ni] = __builtin_amdgcn_mfma_f32_16x16x32_bf16(af[mi], bfv[ni], acc[mi][ni], 0,0,0);
    __syncthreads();
  }

  #pragma unroll
  for(int ni=0;ni<4;ni++){
    int col = colBase + wn*64 + ni*16 + rr;
    float bv = (col < G3) ? bihf[col] : bihb[col - G3];
    int dircol = (col >= G3) ? 1 : 0;
    int cm = col - dircol*G3;
    int g  = cm >> 9;
    int j  = cm & 511;
    int mem = j >> 5, cc = j & 31;
    #pragma unroll
    for(int mi=0;mi<4;mi++){
      int row0 = rowBase + wm*64 + mi*16 + rg*4;
      int tt = row0 >> 6;
      int b0 = row0 & 63;
      int bgx = b0 >> 4, rr0 = b0 & 15;
      size_t ob = (((((size_t)dircol*512 + tt)*4 + bgx)*16 + mem)*3 + g)*512 + rr0*32 + cc;
      C[ob]      = f2bf_bits(acc[mi][ni][0]+bv);
      C[ob+32]   = f2bf_bits(acc[mi][ni][1]+bv);
      C[ob+64]   = f2bf_bits(acc[mi][ni][2]+bv);
      C[ob+96]   = f2bf_bits(acc[mi][ni][3]+bv);
    }
  }
}

// ---------------------------------------------------------------- GEMM: attention, fused tanh + ctx_w dot
__launch_bounds__(256)
__global__ void k_gemm_att(const uint16_t* __restrict__ A, const uint16_t* __restrict__ Bw,
                           const float* __restrict__ attn_b, const float* __restrict__ ctx_w,
                           float* __restrict__ scores_raw)
{
  __shared__ uint16_t lA[2][128*32];
  __shared__ uint16_t lB[2][128*32];
  const int K = 1024;
  int bn = blockIdx.x, bm = blockIdx.y;
  int tid = threadIdx.x;
  int lane = tid & 63, wid = tid >> 6;
  int wm = wid >> 1, wn = wid & 1;
  int rowBase = bm*128, colBase = bn*128;
  int rg = lane >> 4, rr = lane & 15;

  auto stage = [&](int buf, int kt){
    #pragma unroll
    for(int i=0;i<2;i++){
      int e = (i*256 + tid)*8;
      int r = e >> 5, c = e & 31;
      __builtin_amdgcn_global_load_lds((const GLOBAL_AS void*)(A + (size_t)(rowBase + r)*K + kt*32 + c),
                                       (LDS_AS void*)&lA[buf][e], 16, 0, 0);
    }
    #pragma unroll
    for(int i=0;i<2;i++){
      int e = (i*256 + tid)*8;
      int r = e >> 5, c = e & 31;
      __builtin_amdgcn_global_load_lds((const GLOBAL_AS void*)(Bw + (size_t)(colBase + r)*K + kt*32 + c),
                                       (LDS_AS void*)&lB[buf][e], 16, 0, 0);
    }
  };

  f32x4 acc[4][4];
  #pragma unroll
  for(int mi=0;mi<4;mi++)
    #pragma unroll
    for(int ni=0;ni<4;ni++) acc[mi][ni] = (f32x4){0.f,0.f,0.f,0.f};

  stage(0, 0);
  __syncthreads();
  for(int kt=0; kt<32; kt++){
    int buf = kt & 1;
    if(kt+1 < 32) stage(buf^1, kt+1);
    bf16x8 af[4], bfv[4];
    #pragma unroll
    for(int mi=0;mi<4;mi++)
      af[mi] = *(const bf16x8*)&lA[buf][(wm*64 + mi*16 + rr)*32 + rg*8];
    #pragma unroll
    for(int ni=0;ni<4;ni++)
      bfv[ni] = *(const bf16x8*)&lB[buf][(wn*64 + ni*16 + rr)*32 + rg*8];
    #pragma unroll
    for(int mi=0;mi<4;mi++)
      #pragma unroll
      for(int ni=0;ni<4;ni++)
        acc[mi][ni] = __builtin_amdgcn_mfma_f32_16x16x32_bf16(af[mi], bfv[ni], acc[mi][ni], 0,0,0);
    __syncthreads();
  }

  float ab[4], cw[4];
  #pragma unroll
  for(int ni=0;ni<4;ni++){
    int col = colBase + wn*64 + ni*16 + rr;
    ab[ni] = attn_b[col];
    cw[ni] = ctx_w[col];
  }
  #pragma unroll
  for(int mi=0;mi<4;mi++){
    #pragma unroll
    for(int r=0;r<4;r++){
      float part = 0.f;
      #pragma unroll
      for(int ni=0;ni<4;ni++) part += tanhf(acc[mi][ni][r] + ab[ni]) * cw[ni];
      #pragma unroll
      for(int off=1; off<16; off<<=1) part += __shfl_xor(part, off);
      if(rr == 0){
        int row = rowBase + wm*64 + mi*16 + rg*4 + r;
        atomicAdd(&scores_raw[row], part);
      }
    }
  }
}

// ---------------------------------------------------------------- recurrence v13: sentinel poll + single full load.
// r13 protocol (tag-in-data, W in registers), but detection polls only 16 sentinel
// tagged words per wave (128B/round) with s_sleep pacing; the full 32KB tagged batch
// is issued once after sentinels hit, verified, with the r13 retry loop as fallback.
__launch_bounds__(768, 3)
__global__ void k_recur(const uint16_t* __restrict__ xp,     // blocked [dir][T][bg][member][3][16][32]
                        const uint4* __restrict__ wmem,      // pre-swizzled W slices
                        const float* __restrict__ bhhf, const float* __restrict__ bhhb,
                        unsigned long long* __restrict__ tagbuf,
                        uint16_t* __restrict__ f_out)
{
  __shared__ uint16_t hl[16*512];        // 16 KB, chunk-XOR swizzled
  __shared__ float    ghl[2*6*16*17];    // 12.75 KB

  int bid = blockIdx.x;
  int dir = bid & 1, bg = (bid >> 1) & 3, member = bid >> 3;
  int jb = member*32;
  int tid = threadIdx.x;
  int lane = tid & 63, w = tid >> 6;
  int rr = lane & 15, rg = lane >> 4;
  int ct = w >> 1, kh = w & 1;

  // ---- W fragments -> registers (8 x 16B per lane, loop-invariant) ----
  const uint4* wsl = wmem + (size_t)(dir*16 + member)*6144 + (ct*16 + rr)*64;
  int xm = rr & 7;
  uint4 wu0 = wsl[(kh*32 +  0 + rg) ^ xm];
  uint4 wu1 = wsl[(kh*32 +  4 + rg) ^ xm];
  uint4 wu2 = wsl[(kh*32 +  8 + rg) ^ xm];
  uint4 wu3 = wsl[(kh*32 + 12 + rg) ^ xm];
  uint4 wu4 = wsl[(kh*32 + 16 + rg) ^ xm];
  uint4 wu5 = wsl[(kh*32 + 20 + rg) ^ xm];
  uint4 wu6 = wsl[(kh*32 + 24 + rg) ^ xm];
  uint4 wu7 = wsl[(kh*32 + 28 + rg) ^ xm];
  asm volatile("" :: "v"(wu0.x), "v"(wu0.y), "v"(wu0.z), "v"(wu0.w),
                     "v"(wu1.x), "v"(wu1.y), "v"(wu1.z), "v"(wu1.w));
  asm volatile("" :: "v"(wu2.x), "v"(wu2.y), "v"(wu2.z), "v"(wu2.w),
                     "v"(wu3.x), "v"(wu3.y), "v"(wu3.z), "v"(wu3.w));
  asm volatile("" :: "v"(wu4.x), "v"(wu4.y), "v"(wu4.z), "v"(wu4.w),
                     "v"(wu5.x), "v"(wu5.y), "v"(wu5.z), "v"(wu5.w));
  asm volatile("" :: "v"(wu6.x), "v"(wu6.y), "v"(wu6.z), "v"(wu6.w),
                     "v"(wu7.x), "v"(wu7.y), "v"(wu7.z), "v"(wu7.w));

  for(int i = tid; i < 2*6*16*17; i += 768) ghl[i] = 0.f;

  // gate-thread constants: thread (tid<512) owns (row=tid>>5, col=jb+(tid&31))
  int gcol = tid & 31;
  const float* bhh = dir ? bhhb : bhhf;
  float bR = 0.f, bZ = 0.f, bN = 0.f, hprev = 0.f;
  if(tid < 512){
    bR = bhh[jb + gcol];
    bZ = bhh[512 + jb + gcol];
    bN = bhh[1024 + jb + gcol];
  }

  // consumer staging role (tid<512): row, 8 slots (stride 32)
  int srow = tid >> 5;
  int sbase = tid & 31;                   // slot base; slots sbase+32k
  int cswz = ((sbase >> 2) ^ (srow & 7)); // swizzled chunk base
  int lpos0 = srow*512 + cswz*8 + (sbase & 3)*2;

  __syncthreads();   // ghl zeroed

  #pragma unroll 1
  for(int t = 0; t < 512; t++){
    int trow = dir ? (511 - t) : t;

    // xp loads: 3 coalesced 1KB loads (blocked layout); consumed in gate phase
    uint16_t xr16 = 0, xz16 = 0, xn16 = 0;
    if(tid < 512){
      const uint16_t* xb = xp + (((((size_t)dir*512 + trow)*4 + bg)*16 + member)*3)*512;
      xr16 = xb[tid];
      xz16 = xb[512 + tid];
      xn16 = xb[1024 + tid];
    }

    if(t > 0 && tid < 512){
      size_t bufbase = (size_t)((dir*2 + ((t-1) & 1))*4 + bg)*16*256;
      unsigned want = (unsigned)t;
      // sentinel poll: lanes 0-15 of each staging wave watch one member each (row 0, slot m*16)
      {
        const unsigned long long* sb = tagbuf + bufbase;
        unsigned long long sv = (unsigned long long)want;
        while(true){
          if(lane < 16) sv = LDT(sb + (lane << 4));
          if(__all((unsigned)sv == want)) break;
          __builtin_amdgcn_s_sleep(1);
        }
      }
      // full tagged batch (usually hits on the first round), verify, rare retry
      const unsigned long long* tb = tagbuf + bufbase + (size_t)srow*256 + sbase;
      unsigned long long v0,v1,v2,v3,v4,v5,v6,v7;
      bool ok;
      do {
        v0 = LDT(tb+0);   v1 = LDT(tb+32);  v2 = LDT(tb+64);  v3 = LDT(tb+96);
        v4 = LDT(tb+128); v5 = LDT(tb+160); v6 = LDT(tb+192); v7 = LDT(tb+224);
        ok = ((unsigned)v0 == want) & ((unsigned)v1 == want)
           & ((unsigned)v2 == want) & ((unsigned)v3 == want)
           & ((unsigned)v4 == want) & ((unsigned)v5 == want)
           & ((unsigned)v6 == want) & ((unsigned)v7 == want);
      } while(!ok);
      // LDS stage (chunk-XOR swizzled); slot s=sbase+32k -> chunk (cswz + 8k)
      *(uint32_t*)&hl[lpos0 +   0] = (uint32_t)(v0 >> 32);
      *(uint32_t*)&hl[lpos0 +  64] = (uint32_t)(v1 >> 32);
      *(uint32_t*)&hl[lpos0 + 128] = (uint32_t)(v2 >> 32);
      *(uint32_t*)&hl[lpos0 + 192] = (uint32_t)(v3 >> 32);
      *(uint32_t*)&hl[lpos0 + 256] = (uint32_t)(v4 >> 32);
      *(uint32_t*)&hl[lpos0 + 320] = (uint32_t)(v5 >> 32);
      *(uint32_t*)&hl[lpos0 + 384] = (uint32_t)(v6 >> 32);
      *(uint32_t*)&hl[lpos0 + 448] = (uint32_t)(v7 >> 32);
    }
    __syncthreads();   // (A) hl ready

    if(t > 0){
      // gh partial: wave (ct, kh): 16 rows x 16 cols over K-half kh, W from registers
      f32x4 acc = (f32x4){0.f,0.f,0.f,0.f};
      {
        bf16x8 a0 = *(const bf16x8*)&hl[rr*512 + ((kh*32 +  0 + rg) ^ xm)*8];
        acc = __builtin_amdgcn_mfma_f32_16x16x32_bf16(a0, as_bf16x8(wu0), acc, 0,0,0);
        bf16x8 a1 = *(const bf16x8*)&hl[rr*512 + ((kh*32 +  4 + rg) ^ xm)*8];
        acc = __builtin_amdgcn_mfma_f32_16x16x32_bf16(a1, as_bf16x8(wu1), acc, 0,0,0);
        bf16x8 a2 = *(const bf16x8*)&hl[rr*512 + ((kh*32 +  8 + rg) ^ xm)*8];
        acc = __builtin_amdgcn_mfma_f32_16x16x32_bf16(a2, as_bf16x8(wu2), acc, 0,0,0);
        bf16x8 a3 = *(const bf16x8*)&hl[rr*512 + ((kh*32 + 12 + rg) ^ xm)*8];
        acc = __builtin_amdgcn_mfma_f32_16x16x32_bf16(a3, as_bf16x8(wu3), acc, 0,0,0);
        bf16x8 a4 = *(const bf16x8*)&hl[rr*512 + ((kh*32 + 16 + rg) ^ xm)*8];
        acc = __builtin_amdgcn_mfma_f32_16x16x32_bf16(a4, as_bf16x8(wu4), acc, 0,0,0);
        bf16x8 a5 = *(const bf16x8*)&hl[rr*512 + ((kh*32 + 20 + rg) ^ xm)*8];
        acc = __builtin_amdgcn_mfma_f32_16x16x32_bf16(a5, as_bf16x8(wu5), acc, 0,0,0);
        bf16x8 a6 = *(const bf16x8*)&hl[rr*512 + ((kh*32 + 24 + rg) ^ xm)*8];
        acc = __builtin_amdgcn_mfma_f32_16x16x32_bf16(a6, as_bf16x8(wu6), acc, 0,0,0);
        bf16x8 a7 = *(const bf16x8*)&hl[rr*512 + ((kh*32 + 28 + rg) ^ xm)*8];
        acc = __builtin_amdgcn_mfma_f32_16x16x32_bf16(a7, as_bf16x8(wu7), acc, 0,0,0);
      }
      #pragma unroll
      for(int j = 0; j < 4; j++)
        ghl[((kh*6 + ct)*16 + rg*4 + j)*17 + rr] = acc[j];
    }
    __syncthreads();   // (B) ghl ready (zeros at t==0)

    // gates + tagged publish
    if(tid < 512){
      int grow = tid >> 5;
      int c16 = gcol >> 4, cc = gcol & 15;
      float gR = ghl[((0 + c16)*16 + grow)*17 + cc] + ghl[((6  + c16)*16 + grow)*17 + cc] + bR;
      float gZ = ghl[((2 + c16)*16 + grow)*17 + cc] + ghl[((8  + c16)*16 + grow)*17 + cc] + bZ;
      float gN = ghl[((4 + c16)*16 + grow)*17 + cc] + ghl[((10 + c16)*16 + grow)*17 + cc] + bN;
      float rv = sig_f(bf2f_bits(xr16) + gR);
      float zv = sig_f(bf2f_bits(xz16) + gZ);
      float nv = tanh_f(bf2f_bits(xn16) + rv*gN);
      float hnew = (1.f - zv)*nv + zv*hprev;
      hprev = hnew;
      unsigned hb = (unsigned)f2bf_bits(hnew);
      unsigned nb = (unsigned)__shfl_down((int)hb, 1);
      if((tid & 1) == 0){
        unsigned pk = hb | (nb << 16);
        int slot = member*16 + (gcol >> 1);
        unsigned long long pv = ((unsigned long long)pk << 32) | (unsigned)(t + 1);
        __hip_atomic_store(
          tagbuf + ((size_t)((dir*2 + (t & 1))*4 + bg)*16 + grow)*256 + slot,
          pv, __ATOMIC_RELAXED, __HIP_MEMORY_SCOPE_AGENT);
        *(unsigned*)&f_out[((size_t)trow*64 + bg*16 + grow)*1024 + dir*512 + jb + gcol] = pk;
      }
    }
    // no drain barrier: tag carries sync; next iteration's barriers cover LDS hazards
  }
}

// ---------------------------------------------------------------- softmax over T per batch
__global__ void k_softmax(const float* __restrict__ scores_raw, float* __restrict__ wsm){
  __shared__ float sv[512];
  __shared__ float red[8];
  int b = blockIdx.x;
  int tid = threadIdx.x;
  float mymax = -1e30f;
  for(int t = tid; t < 512; t += 256){
    float s = tanhf(scores_raw[t*64 + b]);
    sv[t] = s;
    mymax = fmaxf(mymax, s);
  }
  #pragma unroll
  for(int off=1; off<64; off<<=1) mymax = fmaxf(mymax, __shfl_xor(mymax, off));
  if((tid&63)==0) red[tid>>6] = mymax;
  __syncthreads();
  float bmax = fmaxf(fmaxf(red[0],red[1]), fmaxf(red[2],red[3]));
  __syncthreads();
  float mysum = 0.f;
  for(int t = tid; t < 512; t += 256){
    float e = __expf(sv[t] - bmax);
    sv[t] = e;
    mysum += e;
  }
  #pragma unroll
  for(int off=1; off<64; off<<=1) mysum += __shfl_xor(mysum, off);
  if((tid&63)==0) red[tid>>6] = mysum;
  __syncthreads();
  float inv = 1.f/(red[0]+red[1]+red[2]+red[3]);
  for(int t = tid; t < 512; t += 256) wsm[b*512 + t] = sv[t]*inv;
}

// ---------------------------------------------------------------- ctx[b,d] = sum_t w[b,t] f[t,b,d]
__global__ void k_ctx(const uint16_t* __restrict__ f_out, const float* __restrict__ wsm, float* __restrict__ ctx){
  __shared__ float wloc[512];
  int b = blockIdx.x >> 2, chunk = blockIdx.x & 3;
  int tid = threadIdx.x;
  for(int t = tid; t < 512; t += 256) wloc[t] = wsm[b*512 + t];
  __syncthreads();
  int d = chunk*256 + tid;
  float acc = 0.f;
  #pragma unroll 8
  for(int t = 0; t < 512; t++)
    acc += wloc[t] * bf2f_bits(f_out[(size_t)(t*64 + b)*1024 + d]);
  ctx[b*1024 + d] = acc;
}

// ---------------------------------------------------------------- classifier
__global__ void k_cls1(const float* __restrict__ ctx, const float* __restrict__ w1,
                       const float* __restrict__ b1, float* __restrict__ hid){
  int idx = blockIdx.x*256 + threadIdx.x;   // 32768
  int b = idx >> 9, h = idx & 511;
  float acc = b1[h];
  for(int d = 0; d < 1024; d++) acc += ctx[b*1024 + d] * w1[d*512 + h];
  hid[idx] = fmaxf(acc, 0.f);
}

__global__ void k_cls2(const float* __restrict__ hid, const float* __restrict__ w2,
                       const float* __restrict__ b2, float* __restrict__ out){
  int idx = threadIdx.x;   // 640
  if(idx >= 640) return;
  int b = idx / 10, o = idx % 10;
  float acc = b2[o];
  for(int h = 0; h < 512; h++) acc += hid[b*512 + h] * w2[h*10 + o];
  out[idx] = acc;
}

// ---------------------------------------------------------------- launch
extern "C" void kernel_launch(void* const* d_in, const int* in_sizes, int n_in,
                              void* d_out, int out_size, void* d_ws, size_t ws_size,
                              hipStream_t stream)
{
  const float* emb    = (const float*)d_in[1];
  const float* w_ih_f = (const float*)d_in[2];
  const float* w_hh_f = (const float*)d_in[3];
  const float* b_ih_f = (const float*)d_in[4];
  const float* b_hh_f = (const float*)d_in[5];
  const float* w_ih_b = (const float*)d_in[6];
  const float* w_hh_b = (const float*)d_in[7];
  const float* b_ih_b = (const float*)d_in[8];
  const float* b_hh_b = (const float*)d_in[9];
  const float* attn_w = (const float*)d_in[10];
  const float* attn_b = (const float*)d_in[11];
  const float* ctx_w  = (const float*)d_in[12];
  const float* cls_w1 = (const float*)d_in[13];
  const float* cls_b1 = (const float*)d_in[14];
  const float* cls_w2 = (const float*)d_in[15];
  const float* cls_b2 = (const float*)d_in[16];
  float* out = (float*)d_out;

  char* ws = (char*)d_ws;
  size_t off = 0;
  auto alloc = [&](size_t bytes){ void* p = ws + off; off += (bytes + 255) & ~(size_t)255; return p; };
  uint16_t* femb = (uint16_t*)alloc((size_t)MROWS*DIN*2);      // emb bf16, later overlaid by f_out
  uint16_t* wcat = (uint16_t*)alloc((size_t)NC*DIN*2);
  uint16_t* xp   = (uint16_t*)alloc((size_t)MROWS*NC*2);       // blocked layout
  uint16_t* awT  = (uint16_t*)alloc((size_t)1024*1024*2);
  uint4*    wmem = (uint4*)alloc((size_t)2*16*96*64*16);       // 3 MB pre-swizzled W
  unsigned long long* tagbuf = (unsigned long long*)alloc((size_t)2*2*4*16*256*8);  // 1 MB
  float* scraw   = (float*)alloc((size_t)MROWS*4);
  float* wsm     = (float*)alloc((size_t)B_*T_*4);
  float* ctx     = (float*)alloc((size_t)B_*1024*4);
  float* hid     = (float*)alloc((size_t)B_*512*4);

  (void)hipMemsetAsync(tagbuf, 0, (size_t)2*2*4*16*256*8, stream);
  (void)hipMemsetAsync(scraw, 0, (size_t)MROWS*4, stream);

  k_conv_emb<<<16384, 256, 0, stream>>>(emb, femb, (long)MROWS*DIN/8);
  k_conv_wcat<<<12288, 256, 0, stream>>>(w_ih_f, w_ih_b, wcat, NC*DIN);
  k_conv_awt<<<4096, 256, 0, stream>>>(attn_w, awT, 1024*1024);
  k_conv_whh<<<768, 256, 0, stream>>>(w_hh_f, w_hh_b, wmem);

  k_gemm_xp<<<dim3(24,256), 256, 0, stream>>>(femb, wcat, b_ih_f, b_ih_b, xp);

  k_recur<<<128, 768, 0, stream>>>(xp, wmem, b_hh_f, b_hh_b, tagbuf, femb /* = f_out */);

  k_gemm_att<<<dim3(8,256), 256, 0, stream>>>(femb, awT, attn_b, ctx_w, scraw);
  k_softmax<<<64, 256, 0, stream>>>(scraw, wsm);
  k_ctx<<<256, 256, 0, stream>>>(femb, wsm, ctx);
  k_cls1<<<128, 256, 0, stream>>>(ctx, cls_w1, cls_b1, hid);
  k_cls2<<<1, 640, 0, stream>>>(hid, cls_w2, cls_b2, out);
}

// Round 16
// 1498.610 us; speedup vs baseline: 1.6212x; 1.1323x over previous
//
#include <hip/hip_runtime.h>
#include <stdint.h>

// Problem constants
#define T_   512
#define B_   64
#define DIN  1024
#define HID  512
#define G3   1536     // 3*HID
#define NC   3072     // both dirs of gates
#define MROWS 32768   // T_*B_

typedef __bf16 bf16;
typedef __bf16 bf16x8 __attribute__((ext_vector_type(8)));
typedef float  f32x4  __attribute__((ext_vector_type(4)));

#define GLOBAL_AS __attribute__((address_space(1)))
#define LDS_AS    __attribute__((address_space(3)))

#define LDT(p) __hip_atomic_load((p), __ATOMIC_RELAXED, __HIP_MEMORY_SCOPE_AGENT)

__device__ __forceinline__ uint16_t f2bf_bits(float x){
  union{float f; uint32_t u;} v; v.f = x;
  uint32_t u = v.u;
  u += 0x7FFFu + ((u >> 16) & 1u);   // round-to-nearest-even
  return (uint16_t)(u >> 16);
}
__device__ __forceinline__ float bf2f_bits(uint16_t h){
  union{uint32_t u; float f;} v; v.u = ((uint32_t)h) << 16;
  return v.f;
}
__device__ __forceinline__ float sig_f(float x){
  return 1.f/(1.f + __expf(-x));
}
__device__ __forceinline__ float tanh_f(float x){
  return 1.f - 2.f/(1.f + __expf(2.f*x));
}
__device__ __forceinline__ bf16x8 as_bf16x8(uint4 u){
  union{uint4 a; bf16x8 b;} c; c.a = u; return c.b;
}

// ---------------------------------------------------------------- converts
__global__ void k_conv_emb(const float* __restrict__ src, uint16_t* __restrict__ dst, long n8){
  long i = (long)blockIdx.x*blockDim.x + threadIdx.x;
  if(i >= n8) return;
  const float4* s = (const float4*)src;
  float4 a = s[i*2], b = s[i*2+1];
  uint32_t p0 = (uint32_t)f2bf_bits(a.x) | ((uint32_t)f2bf_bits(a.y) << 16);
  uint32_t p1 = (uint32_t)f2bf_bits(a.z) | ((uint32_t)f2bf_bits(a.w) << 16);
  uint32_t p2 = (uint32_t)f2bf_bits(b.x) | ((uint32_t)f2bf_bits(b.y) << 16);
  uint32_t p3 = (uint32_t)f2bf_bits(b.z) | ((uint32_t)f2bf_bits(b.w) << 16);
  ((uint4*)dst)[i] = make_uint4(p0,p1,p2,p3);
}

__global__ void k_conv_wcat(const float* __restrict__ wf, const float* __restrict__ wb, uint16_t* __restrict__ dst, int n){
  int i = blockIdx.x*256 + threadIdx.x;
  if(i >= n) return;
  float v = (i < G3*DIN) ? wf[i] : wb[i - G3*DIN];
  dst[i] = f2bf_bits(v);
}

__global__ void k_conv_awt(const float* __restrict__ aw, uint16_t* __restrict__ dst, int n){
  int i = blockIdx.x*256 + threadIdx.x;
  if(i >= n) return;
  int e = i >> 10, d = i & 1023;
  dst[i] = f2bf_bits(aw[d*1024 + e]);   // transpose: awT[e][d]
}

// W_hh -> bf16, member-sliced, chunk-XOR-pre-swizzled (same layout as r6-r13).
__global__ void k_conv_whh(const float* __restrict__ wf, const float* __restrict__ wb, uint4* __restrict__ wmem){
  int idx = blockIdx.x*256 + threadIdx.x;   // 196608 total
  if(idx >= 2*16*96*64) return;
  int c  = idx & 63;
  int t2 = idx >> 6;
  int lc = t2 % 96;
  int t3 = t2 / 96;
  int member = t3 & 15, dir = t3 >> 4;
  int ct = lc >> 4, rr = lc & 15;
  int gcol = (ct >> 1)*512 + member*32 + (ct & 1)*16 + rr;
  int csrc = c ^ (lc & 7);
  const float* src = (dir ? wb : wf) + (size_t)gcol*512 + csrc*8;
  float4 f0 = *(const float4*)src;
  float4 f1 = *(const float4*)(src + 4);
  uint32_t p0 = (uint32_t)f2bf_bits(f0.x) | ((uint32_t)f2bf_bits(f0.y) << 16);
  uint32_t p1 = (uint32_t)f2bf_bits(f0.z) | ((uint32_t)f2bf_bits(f0.w) << 16);
  uint32_t p2 = (uint32_t)f2bf_bits(f1.x) | ((uint32_t)f2bf_bits(f1.y) << 16);
  uint32_t p3 = (uint32_t)f2bf_bits(f1.z) | ((uint32_t)f2bf_bits(f1.w) << 16);
  wmem[idx] = make_uint4(p0,p1,p2,p3);
}

// ---------------------------------------------------------------- GEMM: xp = emb @ Wcat^T + bias
// OUTPUT BLOCKED for k_recur: xp[dir][t][bg][member][g][16 rows][32 cols] bf16
__launch_bounds__(256)
__global__ void k_gemm_xp(const uint16_t* __restrict__ A, const uint16_t* __restrict__ Bw,
                          const float* __restrict__ bihf, const float* __restrict__ bihb,
                          uint16_t* __restrict__ C)
{
  __shared__ uint16_t lA[2][128*32];
  __shared__ uint16_t lB[2][128*32];
  const int K = 1024;
  int bn = blockIdx.x, bm = blockIdx.y;
  int tid = threadIdx.x;
  int lane = tid & 63, wid = tid >> 6;
  int wm = wid >> 1, wn = wid & 1;
  int rowBase = bm*128, colBase = bn*128;
  int rg = lane >> 4, rr = lane & 15;

  auto stage = [&](int buf, int kt){
    #pragma unroll
    for(int i=0;i<2;i++){
      int e = (i*256 + tid)*8;
      int r = e >> 5, c = e & 31;
      __builtin_amdgcn_global_load_lds((const GLOBAL_AS void*)(A + (size_t)(rowBase + r)*K + kt*32 + c),
                                       (LDS_AS void*)&lA[buf][e], 16, 0, 0);
    }
    #pragma unroll
    for(int i=0;i<2;i++){
      int e = (i*256 + tid)*8;
      int r = e >> 5, c = e & 31;
      __builtin_amdgcn_global_load_lds((const GLOBAL_AS void*)(Bw + (size_t)(colBase + r)*K + kt*32 + c),
                                       (LDS_AS void*)&lB[buf][e], 16, 0, 0);
    }
  };

  f32x4 acc[4][4];
  #pragma unroll
  for(int mi=0;mi<4;mi++)
    #pragma unroll
    for(int ni=0;ni<4;ni++) acc[mi][ni] = (f32x4){0.f,0.f,0.f,0.f};

  stage(0, 0);
  __syncthreads();
  for(int kt=0; kt<32; kt++){
    int buf = kt & 1;
    if(kt+1 < 32) stage(buf^1, kt+1);
    bf16x8 af[4], bfv[4];
    #pragma unroll
    for(int mi=0;mi<4;mi++)
      af[mi] = *(const bf16x8*)&lA[buf][(wm*64 + mi*16 + rr)*32 + rg*8];
    #pragma unroll
    for(int ni=0;ni<4;ni++)
      bfv[ni] = *(const bf16x8*)&lB[buf][(wn*64 + ni*16 + rr)*32 + rg*8];
    #pragma unroll
    for(int mi=0;mi<4;mi++)
      #pragma unroll
      for(int ni=0;ni<4;ni++)
        acc[mi][ni] = __builtin_amdgcn_mfma_f32_16x16x32_bf16(af[mi], bfv[ni], acc[mi][ni], 0,0,0);
    __syncthreads();
  }

  #pragma unroll
  for(int ni=0;ni<4;ni++){
    int col = colBase + wn*64 + ni*16 + rr;
    float bv = (col < G3) ? bihf[col] : bihb[col - G3];
    int dircol = (col >= G3) ? 1 : 0;
    int cm = col - dircol*G3;
    int g  = cm >> 9;
    int j  = cm & 511;
    int mem = j >> 5, cc = j & 31;
    #pragma unroll
    for(int mi=0;mi<4;mi++){
      int row0 = rowBase + wm*64 + mi*16 + rg*4;
      int tt = row0 >> 6;
      int b0 = row0 & 63;
      int bgx = b0 >> 4, rr0 = b0 & 15;
      size_t ob = (((((size_t)dircol*512 + tt)*4 + bgx)*16 + mem)*3 + g)*512 + rr0*32 + cc;
      C[ob]      = f2bf_bits(acc[mi][ni][0]+bv);
      C[ob+32]   = f2bf_bits(acc[mi][ni][1]+bv);
      C[ob+64]   = f2bf_bits(acc[mi][ni][2]+bv);
      C[ob+96]   = f2bf_bits(acc[mi][ni][3]+bv);
    }
  }
}

// ---------------------------------------------------------------- GEMM: attention, fused tanh + ctx_w dot
__launch_bounds__(256)
__global__ void k_gemm_att(const uint16_t* __restrict__ A, const uint16_t* __restrict__ Bw,
                           const float* __restrict__ attn_b, const float* __restrict__ ctx_w,
                           float* __restrict__ scores_raw)
{
  __shared__ uint16_t lA[2][128*32];
  __shared__ uint16_t lB[2][128*32];
  const int K = 1024;
  int bn = blockIdx.x, bm = blockIdx.y;
  int tid = threadIdx.x;
  int lane = tid & 63, wid = tid >> 6;
  int wm = wid >> 1, wn = wid & 1;
  int rowBase = bm*128, colBase = bn*128;
  int rg = lane >> 4, rr = lane & 15;

  auto stage = [&](int buf, int kt){
    #pragma unroll
    for(int i=0;i<2;i++){
      int e = (i*256 + tid)*8;
      int r = e >> 5, c = e & 31;
      __builtin_amdgcn_global_load_lds((const GLOBAL_AS void*)(A + (size_t)(rowBase + r)*K + kt*32 + c),
                                       (LDS_AS void*)&lA[buf][e], 16, 0, 0);
    }
    #pragma unroll
    for(int i=0;i<2;i++){
      int e = (i*256 + tid)*8;
      int r = e >> 5, c = e & 31;
      __builtin_amdgcn_global_load_lds((const GLOBAL_AS void*)(Bw + (size_t)(colBase + r)*K + kt*32 + c),
                                       (LDS_AS void*)&lB[buf][e], 16, 0, 0);
    }
  };

  f32x4 acc[4][4];
  #pragma unroll
  for(int mi=0;mi<4;mi++)
    #pragma unroll
    for(int ni=0;ni<4;ni++) acc[mi][ni] = (f32x4){0.f,0.f,0.f,0.f};

  stage(0, 0);
  __syncthreads();
  for(int kt=0; kt<32; kt++){
    int buf = kt & 1;
    if(kt+1 < 32) stage(buf^1, kt+1);
    bf16x8 af[4], bfv[4];
    #pragma unroll
    for(int mi=0;mi<4;mi++)
      af[mi] = *(const bf16x8*)&lA[buf][(wm*64 + mi*16 + rr)*32 + rg*8];
    #pragma unroll
    for(int ni=0;ni<4;ni++)
      bfv[ni] = *(const bf16x8*)&lB[buf][(wn*64 + ni*16 + rr)*32 + rg*8];
    #pragma unroll
    for(int mi=0;mi<4;mi++)
      #pragma unroll
      for(int ni=0;ni<4;ni++)
        acc[mi][ni] = __builtin_amdgcn_mfma_f32_16x16x32_bf16(af[mi], bfv[ni], acc[mi][ni], 0,0,0);
    __syncthreads();
  }

  float ab[4], cw[4];
  #pragma unroll
  for(int ni=0;ni<4;ni++){
    int col = colBase + wn*64 + ni*16 + rr;
    ab[ni] = attn_b[col];
    cw[ni] = ctx_w[col];
  }
  #pragma unroll
  for(int mi=0;mi<4;mi++){
    #pragma unroll
    for(int r=0;r<4;r++){
      float part = 0.f;
      #pragma unroll
      for(int ni=0;ni<4;ni++) part += tanhf(acc[mi][ni][r] + ab[ni]) * cw[ni];
      #pragma unroll
      for(int off=1; off<16; off<<=1) part += __shfl_xor(part, off);
      if(rr == 0){
        int row = rowBase + wm*64 + mi*16 + rg*4 + r;
        atomicAdd(&scores_raw[row], part);
      }
    }
  }
}

// ---------------------------------------------------------------- recurrence (r13-proven): tag-in-data + W in registers.
// 8 chains x 16 members, 128 WGs. h published as u64 {2 bf16 | step tag} agent-relaxed
// atomics; consumer's batched tagged load IS the sync. W fragments (32 VGPR/lane) pinned
// via scalar asm anchors. 2 barriers/step. tagbuf memset(0) per launch (replay-safe).
__launch_bounds__(768, 3)
__global__ void k_recur(const uint16_t* __restrict__ xp,     // blocked [dir][T][bg][member][3][16][32]
                        const uint4* __restrict__ wmem,      // pre-swizzled W slices
                        const float* __restrict__ bhhf, const float* __restrict__ bhhb,
                        unsigned long long* __restrict__ tagbuf,
                        uint16_t* __restrict__ f_out)
{
  __shared__ uint16_t hl[16*512];        // 16 KB, chunk-XOR swizzled
  __shared__ float    ghl[2*6*16*17];    // 12.75 KB

  int bid = blockIdx.x;
  int dir = bid & 1, bg = (bid >> 1) & 3, member = bid >> 3;
  int jb = member*32;
  int tid = threadIdx.x;
  int lane = tid & 63, w = tid >> 6;
  int rr = lane & 15, rg = lane >> 4;
  int ct = w >> 1, kh = w & 1;

  // ---- W fragments -> registers (8 x 16B per lane, loop-invariant) ----
  const uint4* wsl = wmem + (size_t)(dir*16 + member)*6144 + (ct*16 + rr)*64;
  int xm = rr & 7;
  uint4 wu0 = wsl[(kh*32 +  0 + rg) ^ xm];
  uint4 wu1 = wsl[(kh*32 +  4 + rg) ^ xm];
  uint4 wu2 = wsl[(kh*32 +  8 + rg) ^ xm];
  uint4 wu3 = wsl[(kh*32 + 12 + rg) ^ xm];
  uint4 wu4 = wsl[(kh*32 + 16 + rg) ^ xm];
  uint4 wu5 = wsl[(kh*32 + 20 + rg) ^ xm];
  uint4 wu6 = wsl[(kh*32 + 24 + rg) ^ xm];
  uint4 wu7 = wsl[(kh*32 + 28 + rg) ^ xm];
  asm volatile("" :: "v"(wu0.x), "v"(wu0.y), "v"(wu0.z), "v"(wu0.w),
                     "v"(wu1.x), "v"(wu1.y), "v"(wu1.z), "v"(wu1.w));
  asm volatile("" :: "v"(wu2.x), "v"(wu2.y), "v"(wu2.z), "v"(wu2.w),
                     "v"(wu3.x), "v"(wu3.y), "v"(wu3.z), "v"(wu3.w));
  asm volatile("" :: "v"(wu4.x), "v"(wu4.y), "v"(wu4.z), "v"(wu4.w),
                     "v"(wu5.x), "v"(wu5.y), "v"(wu5.z), "v"(wu5.w));
  asm volatile("" :: "v"(wu6.x), "v"(wu6.y), "v"(wu6.z), "v"(wu6.w),
                     "v"(wu7.x), "v"(wu7.y), "v"(wu7.z), "v"(wu7.w));

  for(int i = tid; i < 2*6*16*17; i += 768) ghl[i] = 0.f;

  // gate-thread constants: thread (tid<512) owns (row=tid>>5, col=jb+(tid&31))
  int gcol = tid & 31;
  const float* bhh = dir ? bhhb : bhhf;
  float bR = 0.f, bZ = 0.f, bN = 0.f, hprev = 0.f;
  if(tid < 512){
    bR = bhh[jb + gcol];
    bZ = bhh[512 + jb + gcol];
    bN = bhh[1024 + jb + gcol];
  }

  // consumer staging role (tid<512): row, 8 slots (stride 32)
  int srow = tid >> 5;
  int sbase = tid & 31;                   // slot base; slots sbase+32k
  int cswz = ((sbase >> 2) ^ (srow & 7)); // swizzled chunk base
  int lpos0 = srow*512 + cswz*8 + (sbase & 3)*2;

  __syncthreads();   // ghl zeroed

  #pragma unroll 1
  for(int t = 0; t < 512; t++){
    int trow = dir ? (511 - t) : t;

    // xp loads: 3 coalesced 1KB loads (blocked layout); consumed in gate phase
    uint16_t xr16 = 0, xz16 = 0, xn16 = 0;
    if(tid < 512){
      const uint16_t* xb = xp + (((((size_t)dir*512 + trow)*4 + bg)*16 + member)*3)*512;
      xr16 = xb[tid];
      xz16 = xb[512 + tid];
      xn16 = xb[1024 + tid];
    }

    if(t > 0 && tid < 512){
      // tagged h load: batched rounds — each round re-issues ALL 8 independent loads
      const unsigned long long* tb =
        tagbuf + ((size_t)((dir*2 + ((t-1) & 1))*4 + bg)*16 + srow)*256 + sbase;
      unsigned want = (unsigned)t;
      unsigned long long v0,v1,v2,v3,v4,v5,v6,v7;
      bool ok;
      do {
        v0 = LDT(tb+0);   v1 = LDT(tb+32);  v2 = LDT(tb+64);  v3 = LDT(tb+96);
        v4 = LDT(tb+128); v5 = LDT(tb+160); v6 = LDT(tb+192); v7 = LDT(tb+224);
        ok = ((unsigned)v0 == want) & ((unsigned)v1 == want)
           & ((unsigned)v2 == want) & ((unsigned)v3 == want)
           & ((unsigned)v4 == want) & ((unsigned)v5 == want)
           & ((unsigned)v6 == want) & ((unsigned)v7 == want);
      } while(!ok);
      // LDS stage (chunk-XOR swizzled); slot s=sbase+32k -> chunk (cswz + 8k)
      *(uint32_t*)&hl[lpos0 +   0] = (uint32_t)(v0 >> 32);
      *(uint32_t*)&hl[lpos0 +  64] = (uint32_t)(v1 >> 32);
      *(uint32_t*)&hl[lpos0 + 128] = (uint32_t)(v2 >> 32);
      *(uint32_t*)&hl[lpos0 + 192] = (uint32_t)(v3 >> 32);
      *(uint32_t*)&hl[lpos0 + 256] = (uint32_t)(v4 >> 32);
      *(uint32_t*)&hl[lpos0 + 320] = (uint32_t)(v5 >> 32);
      *(uint32_t*)&hl[lpos0 + 384] = (uint32_t)(v6 >> 32);
      *(uint32_t*)&hl[lpos0 + 448] = (uint32_t)(v7 >> 32);
    }
    __syncthreads();   // (A) hl ready

    if(t > 0){
      // gh partial: wave (ct, kh): 16 rows x 16 cols over K-half kh, W from registers
      f32x4 acc = (f32x4){0.f,0.f,0.f,0.f};
      {
        bf16x8 a0 = *(const bf16x8*)&hl[rr*512 + ((kh*32 +  0 + rg) ^ xm)*8];
        acc = __builtin_amdgcn_mfma_f32_16x16x32_bf16(a0, as_bf16x8(wu0), acc, 0,0,0);
        bf16x8 a1 = *(const bf16x8*)&hl[rr*512 + ((kh*32 +  4 + rg) ^ xm)*8];
        acc = __builtin_amdgcn_mfma_f32_16x16x32_bf16(a1, as_bf16x8(wu1), acc, 0,0,0);
        bf16x8 a2 = *(const bf16x8*)&hl[rr*512 + ((kh*32 +  8 + rg) ^ xm)*8];
        acc = __builtin_amdgcn_mfma_f32_16x16x32_bf16(a2, as_bf16x8(wu2), acc, 0,0,0);
        bf16x8 a3 = *(const bf16x8*)&hl[rr*512 + ((kh*32 + 12 + rg) ^ xm)*8];
        acc = __builtin_amdgcn_mfma_f32_16x16x32_bf16(a3, as_bf16x8(wu3), acc, 0,0,0);
        bf16x8 a4 = *(const bf16x8*)&hl[rr*512 + ((kh*32 + 16 + rg) ^ xm)*8];
        acc = __builtin_amdgcn_mfma_f32_16x16x32_bf16(a4, as_bf16x8(wu4), acc, 0,0,0);
        bf16x8 a5 = *(const bf16x8*)&hl[rr*512 + ((kh*32 + 20 + rg) ^ xm)*8];
        acc = __builtin_amdgcn_mfma_f32_16x16x32_bf16(a5, as_bf16x8(wu5), acc, 0,0,0);
        bf16x8 a6 = *(const bf16x8*)&hl[rr*512 + ((kh*32 + 24 + rg) ^ xm)*8];
        acc = __builtin_amdgcn_mfma_f32_16x16x32_bf16(a6, as_bf16x8(wu6), acc, 0,0,0);
        bf16x8 a7 = *(const bf16x8*)&hl[rr*512 + ((kh*32 + 28 + rg) ^ xm)*8];
        acc = __builtin_amdgcn_mfma_f32_16x16x32_bf16(a7, as_bf16x8(wu7), acc, 0,0,0);
      }
      #pragma unroll
      for(int j = 0; j < 4; j++)
        ghl[((kh*6 + ct)*16 + rg*4 + j)*17 + rr] = acc[j];
    }
    __syncthreads();   // (B) ghl ready (zeros at t==0)

    // gates + tagged publish
    if(tid < 512){
      int grow = tid >> 5;
      int c16 = gcol >> 4, cc = gcol & 15;
      float gR = ghl[((0 + c16)*16 + grow)*17 + cc] + ghl[((6  + c16)*16 + grow)*17 + cc] + bR;
      float gZ = ghl[((2 + c16)*16 + grow)*17 + cc] + ghl[((8  + c16)*16 + grow)*17 + cc] + bZ;
      float gN = ghl[((4 + c16)*16 + grow)*17 + cc] + ghl[((10 + c16)*16 + grow)*17 + cc] + bN;
      float rv = sig_f(bf2f_bits(xr16) + gR);
      float zv = sig_f(bf2f_bits(xz16) + gZ);
      float nv = tanh_f(bf2f_bits(xn16) + rv*gN);
      float hnew = (1.f - zv)*nv + zv*hprev;
      hprev = hnew;
      unsigned hb = (unsigned)f2bf_bits(hnew);
      unsigned nb = (unsigned)__shfl_down((int)hb, 1);
      if((tid & 1) == 0){
        unsigned pk = hb | (nb << 16);
        int slot = member*16 + (gcol >> 1);
        unsigned long long pv = ((unsigned long long)pk << 32) | (unsigned)(t + 1);
        __hip_atomic_store(
          tagbuf + ((size_t)((dir*2 + (t & 1))*4 + bg)*16 + grow)*256 + slot,
          pv, __ATOMIC_RELAXED, __HIP_MEMORY_SCOPE_AGENT);
        *(unsigned*)&f_out[((size_t)trow*64 + bg*16 + grow)*1024 + dir*512 + jb + gcol] = pk;
      }
    }
    // no drain barrier: tag carries sync; next iteration's barriers cover LDS hazards
  }
}

// ---------------------------------------------------------------- softmax over T per batch
__global__ void k_softmax(const float* __restrict__ scores_raw, float* __restrict__ wsm){
  __shared__ float sv[512];
  __shared__ float red[8];
  int b = blockIdx.x;
  int tid = threadIdx.x;
  float mymax = -1e30f;
  for(int t = tid; t < 512; t += 256){
    float s = tanhf(scores_raw[t*64 + b]);
    sv[t] = s;
    mymax = fmaxf(mymax, s);
  }
  #pragma unroll
  for(int off=1; off<64; off<<=1) mymax = fmaxf(mymax, __shfl_xor(mymax, off));
  if((tid&63)==0) red[tid>>6] = mymax;
  __syncthreads();
  float bmax = fmaxf(fmaxf(red[0],red[1]), fmaxf(red[2],red[3]));
  __syncthreads();
  float mysum = 0.f;
  for(int t = tid; t < 512; t += 256){
    float e = __expf(sv[t] - bmax);
    sv[t] = e;
    mysum += e;
  }
  #pragma unroll
  for(int off=1; off<64; off<<=1) mysum += __shfl_xor(mysum, off);
  if((tid&63)==0) red[tid>>6] = mysum;
  __syncthreads();
  float inv = 1.f/(red[0]+red[1]+red[2]+red[3]);
  for(int t = tid; t < 512; t += 256) wsm[b*512 + t] = sv[t]*inv;
}

// ---------------------------------------------------------------- ctx[b,d] = sum_t w[b,t] f[t,b,d]
__global__ void k_ctx(const uint16_t* __restrict__ f_out, const float* __restrict__ wsm, float* __restrict__ ctx){
  __shared__ float wloc[512];
  int b = blockIdx.x >> 2, chunk = blockIdx.x & 3;
  int tid = threadIdx.x;
  for(int t = tid; t < 512; t += 256) wloc[t] = wsm[b*512 + t];
  __syncthreads();
  int d = chunk*256 + tid;
  float acc = 0.f;
  #pragma unroll 8
  for(int t = 0; t < 512; t++)
    acc += wloc[t] * bf2f_bits(f_out[(size_t)(t*64 + b)*1024 + d]);
  ctx[b*1024 + d] = acc;
}

// ---------------------------------------------------------------- classifier
__global__ void k_cls1(const float* __restrict__ ctx, const float* __restrict__ w1,
                       const float* __restrict__ b1, float* __restrict__ hid){
  int idx = blockIdx.x*256 + threadIdx.x;   // 32768
  int b = idx >> 9, h = idx & 511;
  float acc = b1[h];
  for(int d = 0; d < 1024; d++) acc += ctx[b*1024 + d] * w1[d*512 + h];
  hid[idx] = fmaxf(acc, 0.f);
}

// parallel k_cls2: one block (64 lanes) per output element; 8 elems/lane + shuffle reduce
__global__ void k_cls2(const float* __restrict__ hid, const float* __restrict__ w2,
                       const float* __restrict__ b2, float* __restrict__ out){
  int idx = blockIdx.x;        // 640 outputs
  int b = idx / 10, o = idx % 10;
  int lane = threadIdx.x;      // 64
  float acc = 0.f;
  #pragma unroll
  for(int k = 0; k < 8; k++){
    int h = lane + k*64;
    acc += hid[b*512 + h] * w2[h*10 + o];
  }
  #pragma unroll
  for(int off = 1; off < 64; off <<= 1) acc += __shfl_xor(acc, off);
  if(lane == 0) out[idx] = acc + b2[o];
}

// ---------------------------------------------------------------- launch
extern "C" void kernel_launch(void* const* d_in, const int* in_sizes, int n_in,
                              void* d_out, int out_size, void* d_ws, size_t ws_size,
                              hipStream_t stream)
{
  const float* emb    = (const float*)d_in[1];
  const float* w_ih_f = (const float*)d_in[2];
  const float* w_hh_f = (const float*)d_in[3];
  const float* b_ih_f = (const float*)d_in[4];
  const float* b_hh_f = (const float*)d_in[5];
  const float* w_ih_b = (const float*)d_in[6];
  const float* w_hh_b = (const float*)d_in[7];
  const float* b_ih_b = (const float*)d_in[8];
  const float* b_hh_b = (const float*)d_in[9];
  const float* attn_w = (const float*)d_in[10];
  const float* attn_b = (const float*)d_in[11];
  const float* ctx_w  = (const float*)d_in[12];
  const float* cls_w1 = (const float*)d_in[13];
  const float* cls_b1 = (const float*)d_in[14];
  const float* cls_w2 = (const float*)d_in[15];
  const float* cls_b2 = (const float*)d_in[16];
  float* out = (float*)d_out;

  char* ws = (char*)d_ws;
  size_t off = 0;
  auto alloc = [&](size_t bytes){ void* p = ws + off; off += (bytes + 255) & ~(size_t)255; return p; };
  uint16_t* femb = (uint16_t*)alloc((size_t)MROWS*DIN*2);      // emb bf16, later overlaid by f_out
  uint16_t* wcat = (uint16_t*)alloc((size_t)NC*DIN*2);
  uint16_t* xp   = (uint16_t*)alloc((size_t)MROWS*NC*2);       // blocked layout
  uint16_t* awT  = (uint16_t*)alloc((size_t)1024*1024*2);
  uint4*    wmem = (uint4*)alloc((size_t)2*16*96*64*16);       // 3 MB pre-swizzled W
  unsigned long long* tagbuf = (unsigned long long*)alloc((size_t)2*2*4*16*256*8);  // 1 MB
  float* scraw   = (float*)alloc((size_t)MROWS*4);
  float* wsm     = (float*)alloc((size_t)B_*T_*4);
  float* ctx     = (float*)alloc((size_t)B_*1024*4);
  float* hid     = (float*)alloc((size_t)B_*512*4);

  (void)hipMemsetAsync(tagbuf, 0, (size_t)2*2*4*16*256*8, stream);
  (void)hipMemsetAsync(scraw, 0, (size_t)MROWS*4, stream);

  k_conv_emb<<<16384, 256, 0, stream>>>(emb, femb, (long)MROWS*DIN/8);
  k_conv_wcat<<<12288, 256, 0, stream>>>(w_ih_f, w_ih_b, wcat, NC*DIN);
  k_conv_awt<<<4096, 256, 0, stream>>>(attn_w, awT, 1024*1024);
  k_conv_whh<<<768, 256, 0, stream>>>(w_hh_f, w_hh_b, wmem);

  k_gemm_xp<<<dim3(24,256), 256, 0, stream>>>(femb, wcat, b_ih_f, b_ih_b, xp);

  k_recur<<<128, 768, 0, stream>>>(xp, wmem, b_hh_f, b_hh_b, tagbuf, femb /* = f_out */);

  k_gemm_att<<<dim3(8,256), 256, 0, stream>>>(femb, awT, attn_b, ctx_w, scraw);
  k_softmax<<<64, 256, 0, stream>>>(scraw, wsm);
  k_ctx<<<256, 256, 0, stream>>>(femb, wsm, ctx);
  k_cls1<<<128, 256, 0, stream>>>(ctx, cls_w1, cls_b1, hid);
  k_cls2<<<640, 64, 0, stream>>>(hid, cls_w2, cls_b2, out);
}